// Round 12
// baseline (327.617 us; speedup 1.0000x reference)
//
#include <hip/hip_runtime.h>
#include <hip/hip_fp16.h>

// ---------------------------------------------------------------------------
// 2-layer GCN, fp32 in/out.  out = b2 + A_hat( relu( A_hat(x@W1) + b1 ) @ W2 )
// A_hat = D^-1/2 (A + I) D^-1/2.
// Round 20: direct-scatter binA.  R19's occupancy null proved binA is
// LDS-pipe/structure-bound, so delete the structure: no 64KB staging, no
// 16-barrier scan, no flush pass.  Pass-1 LDS histogram -> reserve global
// base per bucket -> LDS cursor = base -> pass-2 p=ldsAtomic(cur[b]);
// part[p]=edge (fire-and-forget 8B store; each (block,bucket) run is ~26
// consecutive slots -> line-dense, L2 write-combines).  Per-edge LDS ops
// 6 -> 2.  LDS 75KB -> 2KB.  R13's disaster was per-edge GLOBAL atomics;
// these are LDS atomics + plain stores.  Replay profile unchanged (within-
// bucket order was already timing-dependent across R9-R19, all passed).
// binB/gemm1m/agg1f/agg2 byte-identical to R19 (317.0us verified).
// ---------------------------------------------------------------------------

#define NPB_LOG 9
#define NPB     512                  // nodes per coarse bucket
#define PCAP    17408                // mean 16384 + 8 sigma (P_ovf ~1e-13)
#define NEDG    5120                 // edges per binA block
#define GPAD    16                   // gcur stride in ints (64B line)

typedef _Float16 f16x8 __attribute__((ext_vector_type(8)));
typedef float    f32x4 __attribute__((ext_vector_type(4)));

__global__ void k_initcur(int* __restrict__ gcur, int npart) {
    int i = blockIdx.x * blockDim.x + threadIdx.x;
    if (i < npart) gcur[i * GPAD] = i * PCAP;
}

// Bin edges into npart (<=256) partitions by dst>>9.  Direct scatter:
// histogram -> reserve -> LDS-cursor scatter.  2 LDS atomics/edge total.
__global__ __launch_bounds__(256) void k_binA(const int* __restrict__ src,
                                              const int* __restrict__ dst,
                                              const float* __restrict__ ea,
                                              int* __restrict__ gcur,
                                              uint2* __restrict__ part,
                                              int E, int npart) {
    __shared__ int hist[256];     // pass-1 histogram (counts)
    __shared__ int cur[256];      // pass-2 global-position cursor
    int t = threadIdx.x;
    int c0 = blockIdx.x * NEDG;
    hist[t] = 0;
    __syncthreads();
    // pass 1: histogram
    for (int j = t; j < NEDG; j += 256) {
        int e = c0 + j;
        if (e < E) atomicAdd(&hist[dst[e] >> NPB_LOG], 1);
    }
    __syncthreads();
    // reserve global space per bucket; cursor = reserved base
    int v = hist[t];
    if (t < npart && v > 0) cur[t] = atomicAdd(&gcur[t * GPAD], v);
    __syncthreads();
    // pass 2: scatter edges straight to global at the reserved positions
    for (int j = t; j < NEDG; j += 256) {
        int e = c0 + j;
        if (e < E) {
            int d = dst[e];
            int b = d >> NPB_LOG;
            int p = atomicAdd(&cur[b], 1);
            if (p < (b + 1) * PCAP)
                part[p] = make_uint2((uint)src[e] | ((uint)(d & (NPB - 1)) << 17),
                                     __float_as_uint(ea[e]));
        }
    }
}

// Phase B: one block per bucket.  Exact counting sort into ecsr + dinv + rows.
// Bucket edges staged once into LDS (139KB, occupancy-free at 196 blocks);
// pass-2 scatter reads LDS instead of re-reading part via L2.
__global__ __launch_bounds__(512) void k_binB(const int* __restrict__ gcur,
                                              const uint2* __restrict__ part,
                                              int2* __restrict__ ecsr,
                                              int2* __restrict__ rowdesc,
                                              float* __restrict__ dinv, int n) {
    __shared__ uint2 stag[PCAP];  // 139 KB bucket staging
    __shared__ int   cnt[NPB];
    __shared__ float wsum[NPB];
    __shared__ int   cur[NPB];
    __shared__ int   wsums[8];
    int b = blockIdx.x;
    int t = threadIdx.x;          // blockDim == NPB == 512
    int lane = t & 63, wv = t >> 6;
    cnt[t] = 0; wsum[t] = 0.0f;
    __syncthreads();
    int beg = b * PCAP;
    int len = gcur[b * GPAD] - beg;
    if (len > PCAP) len = PCAP;
    // pass 1: stage to LDS + histogram + weighted degree (from registers)
    for (int j = t; j < len; j += NPB) {
        uint2 ed = part[beg + j];
        stag[j] = ed;
        int dlow = (ed.x >> 17) & (NPB - 1);
        atomicAdd(&cnt[dlow], 1);
        atomicAdd(&wsum[dlow], __uint_as_float(ed.y));
    }
    __syncthreads();
    // shfl-based exclusive scan of cnt across 512 threads (8 waves)
    int v = cnt[t];
    int s = v;
    for (int off = 1; off < 64; off <<= 1) {
        int u = __shfl_up(s, off, 64);
        if (lane >= off) s += u;
    }
    if (lane == 63) wsums[wv] = s;
    __syncthreads();
    if (t < 64) {
        int x = (t < 8) ? wsums[t] : 0;
        for (int off = 1; off < 8; off <<= 1) {
            int u = __shfl_up(x, off, 64);
            if (lane >= off) x += u;
        }
        if (t < 8) wsums[t] = x;    // inclusive wave sums
    }
    __syncthreads();
    int excl = s - v + (wv > 0 ? wsums[wv - 1] : 0);
    cur[t] = excl;
    int node = (b << NPB_LOG) + t;
    if (node < n) {
        rowdesc[node] = make_int2(beg + excl, v);
        dinv[node]    = rsqrtf(1.0f + wsum[t]);
    }
    __syncthreads();
    // pass 2: scatter into exact rows, reading staged edges from LDS
    for (int j = t; j < len; j += NPB) {
        uint2 ed = stag[j];
        int dlow = (ed.x >> 17) & (NPB - 1);
        int p = atomicAdd(&cur[dlow], 1);
        ecsr[beg + p] = make_int2((int)(ed.x & 0x1FFFF), (int)ed.y);
    }
}

// MFMA gemm: xw2[n,64] = fp16( dinv[row] * (x[n,128] @ W1[128,64]) ).
#define XPAD 136
__global__ __launch_bounds__(256) void k_gemm1m(const float* __restrict__ x,
                                                const float* __restrict__ W1,
                                                const float* __restrict__ dinv,
                                                __half* __restrict__ xw2, int n) {
    __shared__ __align__(16) _Float16 xs[64 * XPAD];
    __shared__ __align__(16) _Float16 wt[64 * XPAD];
    int tid = threadIdx.x;
    int row0 = blockIdx.x * 64;
    for (int i = tid; i < 64 * 32; i += 256) {
        int r = i >> 5, k4 = i & 31;
        float4 f = make_float4(0.f, 0.f, 0.f, 0.f);
        int gr = row0 + r;
        if (gr < n) f = ((const float4*)x)[(size_t)gr * 32 + k4];
        union { _Float16 h[4]; uint2 u; } tmp;
        tmp.h[0] = (_Float16)f.x; tmp.h[1] = (_Float16)f.y;
        tmp.h[2] = (_Float16)f.z; tmp.h[3] = (_Float16)f.w;
        *(uint2*)&xs[r * XPAD + k4 * 4] = tmp.u;
    }
    for (int i = tid; i < 128 * 64; i += 256) {
        int k = i >> 6, nn = i & 63;
        wt[nn * XPAD + k] = (_Float16)W1[i];
    }
    __syncthreads();

    int strip = tid >> 6;
    int lane  = tid & 63;
    int quad  = lane >> 4;
    int m     = lane & 15;
    f32x4 acc[4] = {{0,0,0,0},{0,0,0,0},{0,0,0,0},{0,0,0,0}};
#pragma unroll
    for (int kc = 0; kc < 4; ++kc) {
        f16x8 a = *(const f16x8*)&xs[(strip * 16 + m) * XPAD + kc * 32 + quad * 8];
#pragma unroll
        for (int nt = 0; nt < 4; ++nt) {
            f16x8 b = *(const f16x8*)&wt[(nt * 16 + m) * XPAD + kc * 32 + quad * 8];
            acc[nt] = __builtin_amdgcn_mfma_f32_16x16x32_f16(a, b, acc[nt], 0, 0, 0);
        }
    }
    float dv[4];
#pragma unroll
    for (int reg = 0; reg < 4; ++reg) {
        int gr = row0 + strip * 16 + quad * 4 + reg;
        dv[reg] = (gr < n) ? dinv[gr] : 0.0f;
    }
#pragma unroll
    for (int nt = 0; nt < 4; ++nt) {
#pragma unroll
        for (int reg = 0; reg < 4; ++reg) {
            int gr = row0 + strip * 16 + quad * 4 + reg;
            if (gr < n)
                xw2[(size_t)gr * 64 + nt * 16 + m] = __float2half(dv[reg] * acc[nt][reg]);
        }
    }
}

// Layer-1 aggregation fused with relu+b1+W2 dot.  Wave per node, lane=feature.
// inner = xw2[i,:] + sum_e ew * xw2[s,:]   (dinv[s] pre-folded into xw2)
// g[i]  = dinv[i] * sum_f relu(dinv[i]*inner_f + b1_f) * W2_f
// R9-verified schedule: scalar s_load descriptors, 8-wide unroll, 4-way acc.
__global__ __launch_bounds__(256) void k_agg1f(const int2* __restrict__ rowdesc,
                                               const int2* __restrict__ ecsr,
                                               const float* __restrict__ dinv,
                                               const __half* __restrict__ xw2,
                                               const float* __restrict__ b1,
                                               const float* __restrict__ W2,
                                               float* __restrict__ g, int n) {
    int i = blockIdx.x * 4 + (threadIdx.x >> 6);
    int lane = threadIdx.x & 63;
    if (i >= n) return;
    // Wave-uniform row descriptor -> SGPRs; edge loop uses scalar s_loads.
    int2 rd = rowdesc[i];
    int beg = __builtin_amdgcn_readfirstlane(rd.x);
    int len = __builtin_amdgcn_readfirstlane(rd.y);
    const int2* __restrict__ ep = ecsr + beg;

    float a0 = __half2float(xw2[(size_t)i * 64 + lane]);   // self-loop term
    float a1 = 0.0f, a2 = 0.0f, a3 = 0.0f;
    int j = 0;
    for (; j + 8 <= len; j += 8) {
        int2 e0 = ep[j + 0];
        int2 e1 = ep[j + 1];
        int2 e2 = ep[j + 2];
        int2 e3 = ep[j + 3];
        int2 e4 = ep[j + 4];
        int2 e5 = ep[j + 5];
        int2 e6 = ep[j + 6];
        int2 e7 = ep[j + 7];
        float v0 = __half2float(xw2[(size_t)(uint)e0.x * 64 + lane]);
        float v1 = __half2float(xw2[(size_t)(uint)e1.x * 64 + lane]);
        float v2 = __half2float(xw2[(size_t)(uint)e2.x * 64 + lane]);
        float v3 = __half2float(xw2[(size_t)(uint)e3.x * 64 + lane]);
        float v4 = __half2float(xw2[(size_t)(uint)e4.x * 64 + lane]);
        float v5 = __half2float(xw2[(size_t)(uint)e5.x * 64 + lane]);
        float v6 = __half2float(xw2[(size_t)(uint)e6.x * 64 + lane]);
        float v7 = __half2float(xw2[(size_t)(uint)e7.x * 64 + lane]);
        a0 += __int_as_float(e0.y) * v0;
        a1 += __int_as_float(e1.y) * v1;
        a2 += __int_as_float(e2.y) * v2;
        a3 += __int_as_float(e3.y) * v3;
        a0 += __int_as_float(e4.y) * v4;
        a1 += __int_as_float(e5.y) * v5;
        a2 += __int_as_float(e6.y) * v6;
        a3 += __int_as_float(e7.y) * v7;
    }
    for (; j < len; ++j) {
        int2 e = ep[j];
        a0 += __int_as_float(e.y) * __half2float(xw2[(size_t)(uint)e.x * 64 + lane]);
    }
    float acc = (a0 + a1) + (a2 + a3);
    float di = dinv[i];
    float h = fmaxf(di * acc + b1[lane], 0.0f) * W2[lane];
    for (int off = 32; off; off >>= 1) h += __shfl_down(h, off, 64);
    if (lane == 0) g[i] = di * h;
}

// Layer-2 (scalar): out[i] = b2 + dinv[i] * ( g[i] + sum_e ew * g[s] )
__global__ __launch_bounds__(256) void k_agg2(const int2* __restrict__ rowdesc,
                                              const int2* __restrict__ ecsr,
                                              const float* __restrict__ dinv,
                                              const float* __restrict__ g,
                                              const float* __restrict__ b2,
                                              float* __restrict__ out, int n) {
    int i = blockIdx.x * 4 + (threadIdx.x >> 6);
    int lane = threadIdx.x & 63;
    if (i >= n) return;
    int2 rd = rowdesc[i];
    int beg = __builtin_amdgcn_readfirstlane(rd.x);
    int len = __builtin_amdgcn_readfirstlane(rd.y);
    const int2* __restrict__ ep = ecsr + beg;
    float p = 0.0f;
    for (int j = lane; j < len; j += 64) {
        int2 ed = ep[j];
        p += __int_as_float(ed.y) * g[ed.x];
    }
    for (int off = 32; off; off >>= 1) p += __shfl_down(p, off, 64);
    if (lane == 0) out[i] = b2[0] + dinv[i] * (g[i] + p);
}

extern "C" void kernel_launch(void* const* d_in, const int* in_sizes, int n_in,
                              void* d_out, int out_size, void* d_ws, size_t ws_size,
                              hipStream_t stream) {
    const float* x  = (const float*)d_in[0];
    const int*   ei = (const int*)  d_in[1];
    const float* ea = (const float*)d_in[2];
    const float* W1 = (const float*)d_in[3];
    const float* b1 = (const float*)d_in[4];
    const float* W2 = (const float*)d_in[5];
    const float* b2 = (const float*)d_in[6];
    float* out = (float*)d_out;

    int n = in_sizes[0] / 128;
    int E = in_sizes[1] / 2;
    const int* src = ei;
    const int* dst = ei + E;
    int npart = (n + NPB - 1) >> NPB_LOG;      // 196 for n=100k

    // ws layout (4B words):
    //   gcur[256*GPAD] | part[npart*PCAP*2] (xw2 fp16[64n] overlays after
    //   binB) | ecsr[npart*PCAP*2] | rowdesc[2n] | dinv[n] | g[n]
    int*    ws       = (int*)d_ws;
    int*    gcur     = ws;
    uint2*  part     = (uint2*)(ws + 256 * GPAD);
    __half* xw2      = (__half*)part;          // overlay: 128n bytes <= part bytes
    size_t  psz      = (size_t)npart * PCAP;
    int2*   ecsr     = (int2*)(ws + 256 * GPAD + psz * 2);
    int2*   rowdesc  = (int2*)(ws + 256 * GPAD + psz * 4);
    float*  dinv     = (float*)(ws + 256 * GPAD + psz * 4 + (size_t)2 * n);
    float*  g        = dinv + n;

    k_initcur<<<1, 256, 0, stream>>>(gcur, npart);
    k_binA  <<<(E + NEDG - 1) / NEDG, 256, 0, stream>>>(src, dst, ea, gcur, part, E, npart);
    k_binB  <<<npart, NPB, 0, stream>>>(gcur, part, ecsr, rowdesc, dinv, n);
    k_gemm1m<<<(n + 63) / 64, 256, 0, stream>>>(x, W1, dinv, xw2, n);
    k_agg1f <<<(n + 3) / 4, 256, 0, stream>>>(rowdesc, ecsr, dinv, xw2, b1, W2, g, n);
    k_agg2  <<<(n + 3) / 4, 256, 0, stream>>>(rowdesc, ecsr, dinv, g, b2, out, n);
}

// Round 13
// 304.717 us; speedup vs baseline: 1.0752x; 1.0752x over previous
//
#include <hip/hip_runtime.h>
#include <hip/hip_fp16.h>

// ---------------------------------------------------------------------------
// 2-layer GCN, fp32 in/out.  out = b2 + A_hat( relu( A_hat(x@W1) + b1 ) @ W2 )
// A_hat = D^-1/2 (A + I) D^-1/2.
// Round 21: R20's direct-scatter regressed (+10.6) -> binA reverted to the
// R19 staged form (317.0us verified; binA local optimum).  Two cheap cuts:
//  (1) k_initcur launch deleted: gcur cursors are RELATIVE (hipMemsetAsync 0;
//      binA adds b*PCAP after reserve; binB reads count directly).
//  (2) binB pass-1 uses ONE packed 64-bit LDS atomic (count<<40 | fixed-24
//      ew-sum) instead of two (cnt + float wsum).  No field carry (sum <
//      2^31 << 2^40).  Integer adds commute exactly -> dinv now
//      bit-deterministic across replays (safer than R19).
// binB pass-2 / gemm1m / agg1f / agg2 byte-identical to R19.
// ---------------------------------------------------------------------------

#define NPB_LOG 9
#define NPB     512                  // nodes per coarse bucket
#define PCAP    17408                // mean 16384 + 8 sigma (P_ovf ~1e-13)
#define NEDG    5120                 // edges per binA block (48KB LDS)
#define GPAD    16                   // gcur stride in ints (64B line)
#define FIX     16777216.0f          // 2^24 fixed-point scale for ew

typedef _Float16 f16x8 __attribute__((ext_vector_type(8)));
typedef float    f32x4 __attribute__((ext_vector_type(4)));

// Bin edges into npart (<=256) partitions by dst>>9, LDS-staged so global
// writes are bucket-contiguous runs.  gcur starts at 0 (memset); reserved
// base becomes absolute by adding b*PCAP.
__global__ __launch_bounds__(256) void k_binA(const int* __restrict__ src,
                                              const int* __restrict__ dst,
                                              const float* __restrict__ ea,
                                              int* __restrict__ gcur,
                                              uint2* __restrict__ part,
                                              int E, int npart) {
    __shared__ uint2 stag[NEDG];             // 40 KB staging, bucket-sorted
    __shared__ unsigned char stagb[NEDG];    // 5 KB bucket id per slot
    __shared__ int hist[256];                // histogram, then cursor
    __shared__ int lofs[256];                // exclusive block-local offsets
    __shared__ int base[256];                // reserved global base per bucket
    int t = threadIdx.x;
    int c0 = blockIdx.x * NEDG;
    hist[t] = 0;
    __syncthreads();
    // pass 1: histogram
    for (int j = t; j < NEDG; j += 256) {
        int e = c0 + j;
        if (e < E) atomicAdd(&hist[dst[e] >> NPB_LOG], 1);
    }
    __syncthreads();
    // Kogge-Stone scan over 256 entries -> exclusive offsets; reserve global
    int v = hist[t];
    lofs[t] = v;
    __syncthreads();
    for (int off = 1; off < 256; off <<= 1) {
        int u = (t >= off) ? lofs[t - off] : 0;
        __syncthreads();
        lofs[t] += u;
        __syncthreads();
    }
    int excl = lofs[t] - v;
    if (t < npart && v > 0)
        base[t] = atomicAdd(&gcur[t * GPAD], v) + t * PCAP;
    __syncthreads();
    lofs[t] = excl;
    hist[t] = excl;               // reuse as intra-block scatter cursor
    __syncthreads();
    // pass 2: scatter into LDS staging in bucket order
    for (int j = t; j < NEDG; j += 256) {
        int e = c0 + j;
        if (e < E) {
            int d = dst[e];
            int b = d >> NPB_LOG;
            int p = atomicAdd(&hist[b], 1);
            stag[p]  = make_uint2((uint)src[e] | ((uint)(d & (NPB - 1)) << 17),
                                  __float_as_uint(ea[e]));
            stagb[p] = (unsigned char)b;
        }
    }
    __syncthreads();
    // pass 3: flush — consecutive slots in a bucket -> consecutive global addrs
    int nvalid = min(NEDG, E - c0);
    for (int j = t; j < nvalid; j += 256) {
        int b = stagb[j];
        int gp = base[b] + (j - lofs[b]);
        if (gp < (b + 1) * PCAP) part[gp] = stag[j];
    }
}

// Phase B: one block per bucket.  Exact counting sort into ecsr + dinv + rows.
// Bucket edges staged once into LDS; pass-1 histogram+weighted-degree via a
// single packed 64-bit LDS atomic per edge (count<<40 | fixed-24 ew).
__global__ __launch_bounds__(512) void k_binB(const int* __restrict__ gcur,
                                              const uint2* __restrict__ part,
                                              int2* __restrict__ ecsr,
                                              int2* __restrict__ rowdesc,
                                              float* __restrict__ dinv, int n) {
    __shared__ uint2 stag[PCAP];              // 139 KB bucket staging
    __shared__ unsigned long long cntw[NPB];  // 4 KB packed count|wsum
    __shared__ int   cur[NPB];
    __shared__ int   wsums[8];
    int b = blockIdx.x;
    int t = threadIdx.x;          // blockDim == NPB == 512
    int lane = t & 63, wv = t >> 6;
    cntw[t] = 0ull;
    __syncthreads();
    int beg = b * PCAP;
    int len = gcur[b * GPAD];     // relative count (memset-0 cursors)
    if (len > PCAP) len = PCAP;
    // pass 1: stage to LDS + packed histogram/weighted-degree
    for (int j = t; j < len; j += NPB) {
        uint2 ed = part[beg + j];
        stag[j] = ed;
        int dlow = (ed.x >> 17) & (NPB - 1);
        unsigned long long fx =
            (unsigned long long)(unsigned)__float2uint_rn(__uint_as_float(ed.y) * FIX);
        atomicAdd(&cntw[dlow], (1ull << 40) | fx);
    }
    __syncthreads();
    unsigned long long pk = cntw[t];
    int v = (int)(pk >> 40);
    float wsumf = (float)(pk & 0xFFFFFFFFFFull) * (1.0f / FIX);
    // shfl-based exclusive scan of v across 512 threads (8 waves)
    int s = v;
    for (int off = 1; off < 64; off <<= 1) {
        int u = __shfl_up(s, off, 64);
        if (lane >= off) s += u;
    }
    if (lane == 63) wsums[wv] = s;
    __syncthreads();
    if (t < 64) {
        int x = (t < 8) ? wsums[t] : 0;
        for (int off = 1; off < 8; off <<= 1) {
            int u = __shfl_up(x, off, 64);
            if (lane >= off) x += u;
        }
        if (t < 8) wsums[t] = x;    // inclusive wave sums
    }
    __syncthreads();
    int excl = s - v + (wv > 0 ? wsums[wv - 1] : 0);
    cur[t] = excl;
    int node = (b << NPB_LOG) + t;
    if (node < n) {
        rowdesc[node] = make_int2(beg + excl, v);
        dinv[node]    = rsqrtf(1.0f + wsumf);
    }
    __syncthreads();
    // pass 2: scatter into exact rows, reading staged edges from LDS
    for (int j = t; j < len; j += NPB) {
        uint2 ed = stag[j];
        int dlow = (ed.x >> 17) & (NPB - 1);
        int p = atomicAdd(&cur[dlow], 1);
        ecsr[beg + p] = make_int2((int)(ed.x & 0x1FFFF), (int)ed.y);
    }
}

// MFMA gemm: xw2[n,64] = fp16( dinv[row] * (x[n,128] @ W1[128,64]) ).
#define XPAD 136
__global__ __launch_bounds__(256) void k_gemm1m(const float* __restrict__ x,
                                                const float* __restrict__ W1,
                                                const float* __restrict__ dinv,
                                                __half* __restrict__ xw2, int n) {
    __shared__ __align__(16) _Float16 xs[64 * XPAD];
    __shared__ __align__(16) _Float16 wt[64 * XPAD];
    int tid = threadIdx.x;
    int row0 = blockIdx.x * 64;
    for (int i = tid; i < 64 * 32; i += 256) {
        int r = i >> 5, k4 = i & 31;
        float4 f = make_float4(0.f, 0.f, 0.f, 0.f);
        int gr = row0 + r;
        if (gr < n) f = ((const float4*)x)[(size_t)gr * 32 + k4];
        union { _Float16 h[4]; uint2 u; } tmp;
        tmp.h[0] = (_Float16)f.x; tmp.h[1] = (_Float16)f.y;
        tmp.h[2] = (_Float16)f.z; tmp.h[3] = (_Float16)f.w;
        *(uint2*)&xs[r * XPAD + k4 * 4] = tmp.u;
    }
    for (int i = tid; i < 128 * 64; i += 256) {
        int k = i >> 6, nn = i & 63;
        wt[nn * XPAD + k] = (_Float16)W1[i];
    }
    __syncthreads();

    int strip = tid >> 6;
    int lane  = tid & 63;
    int quad  = lane >> 4;
    int m     = lane & 15;
    f32x4 acc[4] = {{0,0,0,0},{0,0,0,0},{0,0,0,0},{0,0,0,0}};
#pragma unroll
    for (int kc = 0; kc < 4; ++kc) {
        f16x8 a = *(const f16x8*)&xs[(strip * 16 + m) * XPAD + kc * 32 + quad * 8];
#pragma unroll
        for (int nt = 0; nt < 4; ++nt) {
            f16x8 b = *(const f16x8*)&wt[(nt * 16 + m) * XPAD + kc * 32 + quad * 8];
            acc[nt] = __builtin_amdgcn_mfma_f32_16x16x32_f16(a, b, acc[nt], 0, 0, 0);
        }
    }
    float dv[4];
#pragma unroll
    for (int reg = 0; reg < 4; ++reg) {
        int gr = row0 + strip * 16 + quad * 4 + reg;
        dv[reg] = (gr < n) ? dinv[gr] : 0.0f;
    }
#pragma unroll
    for (int nt = 0; nt < 4; ++nt) {
#pragma unroll
        for (int reg = 0; reg < 4; ++reg) {
            int gr = row0 + strip * 16 + quad * 4 + reg;
            if (gr < n)
                xw2[(size_t)gr * 64 + nt * 16 + m] = __float2half(dv[reg] * acc[nt][reg]);
        }
    }
}

// Layer-1 aggregation fused with relu+b1+W2 dot.  Wave per node, lane=feature.
// inner = xw2[i,:] + sum_e ew * xw2[s,:]   (dinv[s] pre-folded into xw2)
// g[i]  = dinv[i] * sum_f relu(dinv[i]*inner_f + b1_f) * W2_f
// R9-verified schedule: scalar s_load descriptors, 8-wide unroll, 4-way acc.
__global__ __launch_bounds__(256) void k_agg1f(const int2* __restrict__ rowdesc,
                                               const int2* __restrict__ ecsr,
                                               const float* __restrict__ dinv,
                                               const __half* __restrict__ xw2,
                                               const float* __restrict__ b1,
                                               const float* __restrict__ W2,
                                               float* __restrict__ g, int n) {
    int i = blockIdx.x * 4 + (threadIdx.x >> 6);
    int lane = threadIdx.x & 63;
    if (i >= n) return;
    // Wave-uniform row descriptor -> SGPRs; edge loop uses scalar s_loads.
    int2 rd = rowdesc[i];
    int beg = __builtin_amdgcn_readfirstlane(rd.x);
    int len = __builtin_amdgcn_readfirstlane(rd.y);
    const int2* __restrict__ ep = ecsr + beg;

    float a0 = __half2float(xw2[(size_t)i * 64 + lane]);   // self-loop term
    float a1 = 0.0f, a2 = 0.0f, a3 = 0.0f;
    int j = 0;
    for (; j + 8 <= len; j += 8) {
        int2 e0 = ep[j + 0];
        int2 e1 = ep[j + 1];
        int2 e2 = ep[j + 2];
        int2 e3 = ep[j + 3];
        int2 e4 = ep[j + 4];
        int2 e5 = ep[j + 5];
        int2 e6 = ep[j + 6];
        int2 e7 = ep[j + 7];
        float v0 = __half2float(xw2[(size_t)(uint)e0.x * 64 + lane]);
        float v1 = __half2float(xw2[(size_t)(uint)e1.x * 64 + lane]);
        float v2 = __half2float(xw2[(size_t)(uint)e2.x * 64 + lane]);
        float v3 = __half2float(xw2[(size_t)(uint)e3.x * 64 + lane]);
        float v4 = __half2float(xw2[(size_t)(uint)e4.x * 64 + lane]);
        float v5 = __half2float(xw2[(size_t)(uint)e5.x * 64 + lane]);
        float v6 = __half2float(xw2[(size_t)(uint)e6.x * 64 + lane]);
        float v7 = __half2float(xw2[(size_t)(uint)e7.x * 64 + lane]);
        a0 += __int_as_float(e0.y) * v0;
        a1 += __int_as_float(e1.y) * v1;
        a2 += __int_as_float(e2.y) * v2;
        a3 += __int_as_float(e3.y) * v3;
        a0 += __int_as_float(e4.y) * v4;
        a1 += __int_as_float(e5.y) * v5;
        a2 += __int_as_float(e6.y) * v6;
        a3 += __int_as_float(e7.y) * v7;
    }
    for (; j < len; ++j) {
        int2 e = ep[j];
        a0 += __int_as_float(e.y) * __half2float(xw2[(size_t)(uint)e.x * 64 + lane]);
    }
    float acc = (a0 + a1) + (a2 + a3);
    float di = dinv[i];
    float h = fmaxf(di * acc + b1[lane], 0.0f) * W2[lane];
    for (int off = 32; off; off >>= 1) h += __shfl_down(h, off, 64);
    if (lane == 0) g[i] = di * h;
}

// Layer-2 (scalar): out[i] = b2 + dinv[i] * ( g[i] + sum_e ew * g[s] )
__global__ __launch_bounds__(256) void k_agg2(const int2* __restrict__ rowdesc,
                                              const int2* __restrict__ ecsr,
                                              const float* __restrict__ dinv,
                                              const float* __restrict__ g,
                                              const float* __restrict__ b2,
                                              float* __restrict__ out, int n) {
    int i = blockIdx.x * 4 + (threadIdx.x >> 6);
    int lane = threadIdx.x & 63;
    if (i >= n) return;
    int2 rd = rowdesc[i];
    int beg = __builtin_amdgcn_readfirstlane(rd.x);
    int len = __builtin_amdgcn_readfirstlane(rd.y);
    const int2* __restrict__ ep = ecsr + beg;
    float p = 0.0f;
    for (int j = lane; j < len; j += 64) {
        int2 ed = ep[j];
        p += __int_as_float(ed.y) * g[ed.x];
    }
    for (int off = 32; off; off >>= 1) p += __shfl_down(p, off, 64);
    if (lane == 0) out[i] = b2[0] + dinv[i] * (g[i] + p);
}

extern "C" void kernel_launch(void* const* d_in, const int* in_sizes, int n_in,
                              void* d_out, int out_size, void* d_ws, size_t ws_size,
                              hipStream_t stream) {
    const float* x  = (const float*)d_in[0];
    const int*   ei = (const int*)  d_in[1];
    const float* ea = (const float*)d_in[2];
    const float* W1 = (const float*)d_in[3];
    const float* b1 = (const float*)d_in[4];
    const float* W2 = (const float*)d_in[5];
    const float* b2 = (const float*)d_in[6];
    float* out = (float*)d_out;

    int n = in_sizes[0] / 128;
    int E = in_sizes[1] / 2;
    const int* src = ei;
    const int* dst = ei + E;
    int npart = (n + NPB - 1) >> NPB_LOG;      // 196 for n=100k

    // ws layout (4B words):
    //   gcur[256*GPAD] | part[npart*PCAP*2] (xw2 fp16[64n] overlays after
    //   binB) | ecsr[npart*PCAP*2] | rowdesc[2n] | dinv[n] | g[n]
    int*    ws       = (int*)d_ws;
    int*    gcur     = ws;
    uint2*  part     = (uint2*)(ws + 256 * GPAD);
    __half* xw2      = (__half*)part;          // overlay: 128n bytes <= part bytes
    size_t  psz      = (size_t)npart * PCAP;
    int2*   ecsr     = (int2*)(ws + 256 * GPAD + psz * 2);
    int2*   rowdesc  = (int2*)(ws + 256 * GPAD + psz * 4);
    float*  dinv     = (float*)(ws + 256 * GPAD + psz * 4 + (size_t)2 * n);
    float*  g        = dinv + n;

    hipMemsetAsync(gcur, 0, 256 * GPAD * sizeof(int), stream);
    k_binA  <<<(E + NEDG - 1) / NEDG, 256, 0, stream>>>(src, dst, ea, gcur, part, E, npart);
    k_binB  <<<npart, NPB, 0, stream>>>(gcur, part, ecsr, rowdesc, dinv, n);
    k_gemm1m<<<(n + 63) / 64, 256, 0, stream>>>(x, W1, dinv, xw2, n);
    k_agg1f <<<(n + 3) / 4, 256, 0, stream>>>(rowdesc, ecsr, dinv, xw2, b1, W2, g, n);
    k_agg2  <<<(n + 3) / 4, 256, 0, stream>>>(rowdesc, ecsr, dinv, g, b2, out, n);
}